// Round 7
// baseline (190.793 us; speedup 1.0000x reference)
//
#include <hip/hip_runtime.h>

typedef __bf16 bf16x8 __attribute__((ext_vector_type(8)));
typedef float f32x4 __attribute__((ext_vector_type(4)));
typedef float f32x16 __attribute__((ext_vector_type(16)));
typedef unsigned short u16;

#define IN_F 4096
#define OUT_F 4096
#define NTOK 4096
#define RANK 32
#define KEXT 4160              /* 4096 + 32 lora cols + 32 zero pad -> 65 K-tiles of 64 */
#define NT 65
#define ROWB ((size_t)KEXT * 2) /* row stride bytes = 8320 */
#define D1 65536               /* LDS byte offset of dbuf1 */

// round-to-nearest-even f32 -> bf16
__device__ __forceinline__ u16 f2bf(float f) {
  union { float f; unsigned u; } c; c.f = f;
  unsigned u = c.u;
  return (u16)((u + 0x7FFFu + ((u >> 16) & 1u)) >> 16);
}

__device__ __forceinline__ void gload_lds16(const void* g, void* l) {
  __builtin_amdgcn_global_load_lds((const __attribute__((address_space(1))) void*)g,
                                   (__attribute__((address_space(3))) void*)l,
                                   16, 0, 0);
}

// ---------------- prep: per-token amax -> ascale, write bf16 int codes + zero pad ----------------
__global__ __launch_bounds__(256) void prep_kernel(const float* __restrict__ x,
                                                   u16* __restrict__ A,
                                                   float* __restrict__ ascale) {
  int t = blockIdx.x;
  int tid = threadIdx.x;
  const float4* xr = (const float4*)(x + (size_t)t * IN_F);
  float4 v[4];
  float m = 0.f;
#pragma unroll
  for (int i = 0; i < 4; ++i) {
    v[i] = xr[tid + i * 256];
    m = fmaxf(m, fmaxf(fmaxf(fabsf(v[i].x), fabsf(v[i].y)),
                       fmaxf(fabsf(v[i].z), fabsf(v[i].w))));
  }
#pragma unroll
  for (int off = 32; off > 0; off >>= 1) m = fmaxf(m, __shfl_xor(m, off));
  __shared__ float wmax[4];
  if ((tid & 63) == 0) wmax[tid >> 6] = m;
  __syncthreads();
  m = fmaxf(fmaxf(wmax[0], wmax[1]), fmaxf(wmax[2], wmax[3]));
  float as = fmaxf(m, 1e-6f) / 7.f;
  float inv = 1.f / as;
  if (tid == 0) ascale[t] = as;
  u16* Ar = A + (size_t)t * KEXT;
#pragma unroll
  for (int i = 0; i < 4; ++i) {
    float q0 = fminf(fmaxf(rintf(v[i].x * inv), -8.f), 7.f);
    float q1 = fminf(fmaxf(rintf(v[i].y * inv), -8.f), 7.f);
    float q2 = fminf(fmaxf(rintf(v[i].z * inv), -8.f), 7.f);
    float q3 = fminf(fmaxf(rintf(v[i].w * inv), -8.f), 7.f);
    ushort4 u;
    u.x = f2bf(q0); u.y = f2bf(q1); u.z = f2bf(q2); u.w = f2bf(q3);
    *(ushort4*)(Ar + (size_t)(tid + i * 256) * 4) = u;
  }
  if (tid < 8) {  // zero pad cols 4128..4159
    ushort4 z; z.x = z.y = z.z = z.w = 0;
    *(ushort4*)(Ar + IN_F + 32 + tid * 4) = z;
  }
}

// ---------------- dequant: int4 codes * group scale -> bf16, append lora_up + zero pad ----------------
__global__ __launch_bounds__(256) void dequant_kernel(const int* __restrict__ qw,
                                                      const float* __restrict__ wscale,
                                                      const float* __restrict__ lu,
                                                      u16* __restrict__ B) {
  int o = blockIdx.x;
  int tid = threadIdx.x;
  const int4* qr = (const int4*)(qw + (size_t)o * IN_F);
  const float* sr = wscale + (size_t)o * (IN_F / 64);
  u16* Br = B + (size_t)o * KEXT;
#pragma unroll
  for (int s = 0; s < 4; ++s) {
    int e = tid + s * 256;
    int4 q = qr[e];
    float sc = sr[e >> 4];
    ushort4 u;
    u.x = f2bf((float)q.x * sc);
    u.y = f2bf((float)q.y * sc);
    u.z = f2bf((float)q.z * sc);
    u.w = f2bf((float)q.w * sc);
    *(ushort4*)(Br + (size_t)4 * e) = u;
  }
  if (tid < RANK) Br[IN_F + tid] = f2bf(lu[(size_t)o * RANK + tid]);
  if (tid < 8) {
    ushort4 z; z.x = z.y = z.z = z.w = 0;
    *(ushort4*)(Br + IN_F + 32 + tid * 4) = z;
  }
}

// ---------------- lorad: tr = x @ ld^T, split-K=8 partials ----------------
__global__ __launch_bounds__(256) void lorad_kernel(const float* __restrict__ x,
                                                    const float* __restrict__ ld,
                                                    float* __restrict__ tr8) {
  __shared__ float Xs[128][68];
  __shared__ float Ls[32][68];
  int b = blockIdx.x;
  int t0 = (b >> 3) * 128;
  int kbase = (b & 7) * 512;
  int tid = threadIdx.x;
  int rb = tid & 7;
  int tb = tid >> 3;
  float acc[4][4];
#pragma unroll
  for (int i = 0; i < 4; ++i)
#pragma unroll
    for (int j = 0; j < 4; ++j) acc[i][j] = 0.f;

  for (int kc = 0; kc < 512; kc += 64) {
    int k0 = kbase + kc;
    __syncthreads();
#pragma unroll
    for (int s = 0; s < 8; ++s) {
      int e = tid + s * 256;
      int row = e >> 4, c4 = (e & 15) * 4;
      float4 vv = *(const float4*)(x + (size_t)(t0 + row) * IN_F + k0 + c4);
      *(float4*)&Xs[row][c4] = vv;
    }
#pragma unroll
    for (int s = 0; s < 2; ++s) {
      int e = tid + s * 256;
      int row = e >> 4, c4 = (e & 15) * 4;
      float4 vv = *(const float4*)(ld + (size_t)row * IN_F + k0 + c4);
      *(float4*)&Ls[row][c4] = vv;
    }
    __syncthreads();
    for (int k4 = 0; k4 < 64; k4 += 4) {
      float4 lv[4], xv[4];
#pragma unroll
      for (int r = 0; r < 4; ++r) lv[r] = *(float4*)&Ls[rb + r * 8][k4];
#pragma unroll
      for (int mm = 0; mm < 4; ++mm) xv[mm] = *(float4*)&Xs[tb + mm * 32][k4];
#pragma unroll
      for (int mm = 0; mm < 4; ++mm)
#pragma unroll
        for (int r = 0; r < 4; ++r)
          acc[mm][r] += xv[mm].x * lv[r].x + xv[mm].y * lv[r].y +
                        xv[mm].z * lv[r].z + xv[mm].w * lv[r].w;
    }
  }
  float* dst = tr8 + (size_t)(b & 7) * NTOK * RANK;
#pragma unroll
  for (int mm = 0; mm < 4; ++mm)
#pragma unroll
    for (int r = 0; r < 4; ++r)
      dst[(size_t)(t0 + tb + mm * 32) * RANK + rb + r * 8] = acc[mm][r];
}

// ---------------- trwrite ----------------
__global__ __launch_bounds__(256) void trwrite_kernel(const float* __restrict__ tr8,
                                                      const float* __restrict__ ascale,
                                                      u16* __restrict__ A) {
  int idx = blockIdx.x * 256 + threadIdx.x;
  int t = idx >> 5, r = idx & 31;
  float s = 0.f;
#pragma unroll
  for (int k = 0; k < 8; ++k) s += tr8[(size_t)k * NTOK * RANK + idx];
  A[(size_t)t * KEXT + IN_F + r] = f2bf(s / ascale[t]);
}

// ---------------- main GEMM: 256x256, BK=64, 8 waves, 32x32x16 MFMA, read-ahead 8-phase ----------------
// LDS: dbuf d at d*65536: A 256x128B rows at +0 (halves A0 rows0-127, A1 128-255
// at +16384); B same at +32768. Swizzle: 16B chunk u of row r holds global
// chunk u^(r&7); staging pre-swizzles the GLOBAL source, ds_read XORs -> 0 conflicts.
//
// KEY CHANGE vs r6: per phase, the ds_reads issued are for the NEXT phase's
// MFMA (issued post-barrier, before this phase's MFMA cluster) -> LDS reads
// drain under the MFMA shadow in-wave. MFMA(k) operands were read in phase
// k-1 and are drained by PH_SYNC's lgkmcnt(0) (~free). 32x32x16 MFMA: 8/phase,
// A-frag: lane row=l&31, K-octet=l>>5 (extrapolated from verified 16x16x32);
// C/D: col=l&31, row=(reg&3)+8*(reg>>2)+4*(l>>5) (m74/m101 verified).
//
// Read slots (per 2-tile iter u; T0=2u dbuf0, T1=2u+1 dbuf1):
//   P1-pre: B0(T0)  P1-slot: B1(T0)  P2-slot: A1(T0)  P4-slot: A0(T1)
//   P5-pre: B0(T1)  P5-slot: B1(T1)  P6-slot: A1(T1)  P8-slot: A0(T0')
// Stage slots (UNCHANGED from r6): P1:A1d1 | P3:B0,B1d0 | P4:A0,A1d0 (vmcnt6)
//   | P7:B0d1 | P8:B1,A0d1 (vmcnt4).  Ledger re-proven: every staged region's
// last reader has its own lgkm0 (at the following PH_SYNC) before a barrier the
// stager must cross; vmcnt(6)@P4 forces dbuf1 complete (incl P1's A1d1) before
// P4-slot/P5+ reads; vmcnt(4)@P8 forces dbuf0 (P3,P4) before P8-slot/P1' reads.
// PH_END needed only before stage-bearing phases: after P2,P3,P6,P7,P8.

#define PH_SYNC() do { __builtin_amdgcn_sched_barrier(0); \
                       asm volatile("s_barrier" ::: "memory"); \
                       asm volatile("s_waitcnt lgkmcnt(0)" ::: "memory"); \
                       __builtin_amdgcn_sched_barrier(0); } while (0)
#define PH_END() do { __builtin_amdgcn_sched_barrier(0); \
                      asm volatile("s_barrier" ::: "memory"); } while (0)

#define STAGE_A(dbase, H, src) do { \
  const char* s_ = (src) + (size_t)(H) * (128 * ROWB); \
  char* l_ = smem + (dbase) + (H) * 16384 + tid * 16; \
  gload_lds16(s_, l_); \
  gload_lds16(s_ + (size_t)64 * ROWB, l_ + 8192); } while (0)

#define STAGE_B(dbase, H, src) do { \
  const char* s_ = (src) + (size_t)(H) * (128 * ROWB); \
  char* l_ = smem + (dbase) + 32768 + (H) * 16384 + tid * 16; \
  gload_lds16(s_, l_); \
  gload_lds16(s_ + (size_t)64 * ROWB, l_ + 8192); } while (0)

// A half h (2 M-blocks of 32 rows), 4 K-steps: 8 x ds_read_b128
#define READ_A32(dst, dbase, h) \
  _Pragma("unroll") for (int m2_ = 0; m2_ < 2; ++m2_) \
  _Pragma("unroll") for (int s_ = 0; s_ < 4; ++s_) \
    dst[m2_ * 4 + s_] = *(const bf16x8*)(smem + (dbase) + aoff + (h) * 8192 + m2_ * 4096 + colz[s_]);

// B N-block u (32 cols), 4 K-steps: 4 x ds_read_b128
#define READ_B32(dst, dbase, u) \
  _Pragma("unroll") for (int s_ = 0; s_ < 4; ++s_) \
    dst[s_] = *(const bf16x8*)(smem + (dbase) + boff + (u) * 4096 + colz[s_]);

// one quadrant: 2 M-blocks x 1 N-block x K=64 -> 8 MFMA (s outer = 2 indep chains)
#define MFMAQ32(aH, bH, mb, n) do { \
  __builtin_amdgcn_s_setprio(1); \
  _Pragma("unroll") for (int s_ = 0; s_ < 4; ++s_) \
  _Pragma("unroll") for (int m2_ = 0; m2_ < 2; ++m2_) \
    acc[(mb) + m2_][n] = __builtin_amdgcn_mfma_f32_32x32x16_bf16(aH[m2_ * 4 + s_], bH[s_], acc[(mb) + m2_][n], 0, 0, 0); \
  __builtin_amdgcn_s_setprio(0); } while (0)

__global__ __launch_bounds__(512, 2) void gemm_kernel(const u16* __restrict__ A,
                                                      const u16* __restrict__ B,
                                                      const float* __restrict__ ascale,
                                                      const float* __restrict__ bias,
                                                      float* __restrict__ out) {
  __shared__ __align__(16) char smem[131072];
  int b = blockIdx.x;
  int swz = (b & 7) * 32 + (b >> 3);     // 256 blocks, 8 XCDs -> bijective
  int by = swz >> 4, bx = swz & 15;
  int tm = by * 256, tn = bx * 256;
  int tid = threadIdx.x;
  int lane = tid & 63, wid = tid >> 6;
  int wr = wid >> 2, wc = wid & 3;       // 2x4 wave grid; wave owns 128x64 of C
  int l31 = lane & 31, l5 = lane >> 5;
  int xorb = (lane & 7) << 4;            // row&7 -> 16B-chunk XOR (bits 4-6)
  int colz[4];
#pragma unroll
  for (int s = 0; s < 4; ++s) colz[s] = (s * 32 + l5 * 16) ^ xorb;
  int aoff = wr * 16384 + l31 * 128;             // A row = wr*128 + h*64 + m2*32 + l31
  int boff = 32768 + wc * 8192 + l31 * 128;      // B row = wc*64 + u*32 + l31

  // staging source base: thread covers rows (tid>>3) + {0,64}, pre-swizzled chunk
  int cb = (((tid & 7) ^ ((tid >> 3) & 7)) << 4);
  const char* ag = (const char*)A + (size_t)(tm + (tid >> 3)) * ROWB + cb;
  const char* bg = (const char*)B + (size_t)(tn + (tid >> 3)) * ROWB + cb;

  f32x16 acc[4][2];
#pragma unroll
  for (int i = 0; i < 4; ++i)
#pragma unroll
    for (int j = 0; j < 2; ++j)
#pragma unroll
      for (int e = 0; e < 16; ++e) acc[i][j][e] = 0.f;

  // prologue: tile0 full -> dbuf0; tile1 B0,B1,A0 -> dbuf1 (steady-state image)
  STAGE_A(0, 0, ag);  STAGE_A(0, 1, ag);
  STAGE_B(0, 0, bg);  STAGE_B(0, 1, bg);
  STAGE_B(D1, 0, bg + 128);  STAGE_B(D1, 1, bg + 128);
  STAGE_A(D1, 0, ag + 128);
  asm volatile("s_waitcnt vmcnt(6)" ::: "memory");  // tile0 landed; tile1 parts in flight
  PH_END();

  const char* agT = ag;   // tile 2u base (+= 256 per iter)
  const char* bgT = bg;
  bf16x8 aS0[8], aS1[8], bU0[4], bU1[4];

  READ_A32(aS0, 0, 0);    // A0(T0) pre-read (P8-slot image)

  for (int u = 0; u < 32; ++u) {
    bool s78 = (2 * u + 3) < NT;   // tile 2u+3 exists?

    // ---- P1: pre: read B0(T0), stage A1d1(2u+1) | slot: read B1(T0) | MFMA Q(A0,B0) ----
    READ_B32(bU0, 0, 0);
    STAGE_A(D1, 1, agT + 128);
    PH_SYNC();
    READ_B32(bU1, 0, 1);
    __builtin_amdgcn_sched_barrier(0);
    MFMAQ32(aS0, bU0, 0, 0);
    // (no END: P2 has no pre-region stage)

    // ---- P2: slot: read A1(T0) | MFMA Q(A0,B1) ----
    PH_SYNC();
    READ_A32(aS1, 0, 1);
    __builtin_amdgcn_sched_barrier(0);
    MFMAQ32(aS0, bU1, 0, 1);
    PH_END();

    // ---- P3: pre: stage B0d0,B1d0(2u+2) | MFMA Q(A1,B1) ----
    STAGE_B(0, 0, bgT + 256);
    STAGE_B(0, 1, bgT + 256);
    PH_SYNC();
    MFMAQ32(aS1, bU1, 2, 1);
    PH_END();

    // ---- P4: pre: stage A0d0,A1d0(2u+2); vmcnt(6) | slot: read A0(T1) | MFMA Q(A1,B0) ----
    STAGE_A(0, 0, agT + 256);
    STAGE_A(0, 1, agT + 256);
    asm volatile("s_waitcnt vmcnt(6)" ::: "memory");  // dbuf1 (P7',P8',P1) landed
    PH_SYNC();
    READ_A32(aS0, D1, 0);
    __builtin_amdgcn_sched_barrier(0);
    MFMAQ32(aS1, bU0, 2, 0);
    // (no END: P5 pre is read-only)

    // ---- P5: pre: read B0(T1) | slot: read B1(T1) | MFMA Q(A0,B0) ----
    READ_B32(bU0, D1, 0);
    PH_SYNC();
    READ_B32(bU1, D1, 1);
    __builtin_amdgcn_sched_barrier(0);
    MFMAQ32(aS0, bU0, 0, 0);
    // (no END: P6 has no pre-region stage)

    // ---- P6: slot: read A1(T1) | MFMA Q(A0,B1) ----
    PH_SYNC();
    READ_A32(aS1, D1, 1);
    __builtin_amdgcn_sched_barrier(0);
    MFMAQ32(aS0, bU1, 0, 1);
    PH_END();

    // ---- P7: pre: stage B0d1(2u+3) | MFMA Q(A1,B1) ----
    if (s78) STAGE_B(D1, 0, bgT + 384);
    PH_SYNC();
    MFMAQ32(aS1, bU1, 2, 1);
    PH_END();

    // ---- P8: pre: stage B1d1,A0d1(2u+3); vmcnt | slot: read A0(T0') | MFMA Q(A1,B0) ----
    if (s78) {
      STAGE_B(D1, 1, bgT + 384);
      STAGE_A(D1, 0, agT + 384);
      asm volatile("s_waitcnt vmcnt(4)" ::: "memory");  // dbuf0 (P3,P4) landed
    } else {
      asm volatile("s_waitcnt vmcnt(0)" ::: "memory");  // tail: drain everything
    }
    PH_SYNC();
    READ_A32(aS0, 0, 0);
    __builtin_amdgcn_sched_barrier(0);
    MFMAQ32(aS1, bU0, 2, 0);
    PH_END();

    agT += 256;
    bgT += 256;
  }

  // ---- tail: tile 64 from dbuf0, free-flow (aS0 pre-read at u31 P8-slot) ----
  READ_B32(bU0, 0, 0);
  READ_B32(bU1, 0, 1);
  READ_A32(aS1, 0, 1);
  asm volatile("s_waitcnt lgkmcnt(0)" ::: "memory");
  __builtin_amdgcn_sched_barrier(0);
  MFMAQ32(aS0, bU0, 0, 0);
  MFMAQ32(aS0, bU1, 0, 1);
  MFMAQ32(aS1, bU1, 2, 1);
  MFMAQ32(aS1, bU0, 2, 0);

  // ---- epilogue: C = acc * ascale[row] + bias[col]; 32x32 C/D layout ----
#pragma unroll
  for (int m = 0; m < 4; ++m) {
#pragma unroll
    for (int n = 0; n < 2; ++n) {
      int col = tn + wc * 64 + n * 32 + l31;
      float bv = bias[col];
#pragma unroll
      for (int g = 0; g < 4; ++g) {
#pragma unroll
        for (int q = 0; q < 4; ++q) {
          int row = tm + wr * 128 + m * 32 + 8 * g + 4 * l5 + q;
          out[(size_t)row * OUT_F + col] = acc[m][n][4 * g + q] * ascale[row] + bv;
        }
      }
    }
  }
}

extern "C" void kernel_launch(void* const* d_in, const int* in_sizes, int n_in,
                              void* d_out, int out_size, void* d_ws, size_t ws_size,
                              hipStream_t stream) {
  const float* x = (const float*)d_in[0];
  const int* qw = (const int*)d_in[1];
  const float* wscale = (const float*)d_in[2];
  const float* ld = (const float*)d_in[3];
  const float* lu = (const float*)d_in[4];
  const float* bias = (const float*)d_in[5];
  float* out = (float*)d_out;

  char* ws = (char*)d_ws;
  const size_t szA = (size_t)NTOK * KEXT * sizeof(u16);
  const size_t szB = (size_t)OUT_F * KEXT * sizeof(u16);
  u16* Aext = (u16*)ws;
  u16* Bext = (u16*)(ws + szA);
  float* ascale = (float*)(ws + szA + szB);
  float* tr8 = (float*)(ws + szA + szB + 16384);

  prep_kernel<<<NTOK, 256, 0, stream>>>(x, Aext, ascale);
  dequant_kernel<<<OUT_F, 256, 0, stream>>>(qw, wscale, lu, Bext);
  lorad_kernel<<<256, 256, 0, stream>>>(x, ld, tr8);
  trwrite_kernel<<<NTOK * RANK / 256, 256, 0, stream>>>(tr8, ascale, Aext);
  gemm_kernel<<<(NTOK / 256) * (OUT_F / 256), 512, 0, stream>>>(Aext, Bext, ascale, bias, out);
}